// Round 3
// 172.844 us; speedup vs baseline: 1.0633x; 1.0633x over previous
//
#include <hip/hip_runtime.h>

#define C_DIM   128
#define O_MAX   10
#define BN_EPS  1e-5f
#define SLOPE   0.2f

typedef short s8v  __attribute__((ext_vector_type(8)));   // 8 bf16 (4 VGPRs)
typedef float f4v  __attribute__((ext_vector_type(4)));   // MFMA accumulator
#define MFMA(a,b,c) __builtin_amdgcn_mfma_f32_16x16x32_bf16(a,b,c,0,0,0)

__device__ inline unsigned short f2bf(float f) {          // RNE fp32->bf16
    unsigned u = __float_as_uint(f);
    unsigned r = u + 0x7FFFu + ((u >> 16) & 1u);
    return (unsigned short)(r >> 16);
}

// ---------------------------------------------------------------------------
// prep: w1n[n=(kk,oc)][c=128] bf16 ; w2b[oc][k2=tap*64+c] bf16 (tight 576) ;
// zero BN sums.
// ---------------------------------------------------------------------------
#define N_W1N  73728
#define N_W2B  18432       /* 32*576 */
__global__ __launch_bounds__(256) void prep(
    const float* __restrict__ w1, const float* __restrict__ w2,
    short* __restrict__ w1n, short* __restrict__ w2b,
    float* __restrict__ sums)
{
    int i = blockIdx.x * 256 + threadIdx.x;
    if (i < N_W1N) {                       // w1n[n][c] = w1[oc][c][kk], n=kk*64+oc
        int n = i >> 7, c = i & 127;
        int kk = n >> 6, oc = n & 63;
        w1n[i] = f2bf(w1[oc * 1152 + c * 9 + kk]);
        return;
    }
    i -= N_W1N;
    if (i < N_W2B) {                       // w2b[oc][k2], k2 = tap*64+c
        int oc = i / 576, k2 = i % 576;
        int tap = k2 >> 6, c = k2 & 63;
        w2b[i] = f2bf(w2[oc * 576 + c * 9 + tap]);
        return;
    }
    i -= N_W2B;
    if (i < 96) sums[i] = 0.f;
}

// ---------------------------------------------------------------------------
// stage1 (per-b block, 256 thr, LDS-limited 5 blocks/CU):
//   phase0: LBF bf16 (stride 136), TH, zero tails
//   phase1: CPT computed DIRECTLY from theta (no COVf staging) + A-GEMM MFMA
//           (LBF x w1n-global) scattered to AT2
//   phase3: conv1 MFMA -> lrelu -> H1T (overlay) ; phase4: im2col -> H2C ;
//   phase5: conv2 MFMA full-K on waves 0,1 (no SCR split) ; BN2 sums.
// LDS (bytes): CPT 0..13312 | AT2 13312..26624 | LBF 26624..30976 |
//   TH 32000..32240 | CS 32240..32368 | CS2 32368..32496
// overlays (CPT/AT2/LBF dead): H1T 0..13200 | H2C 13312..32000
// total 32496 -> <= 32 KiB -> 5 blocks/CU (VGPR 68 is not the limiter)
// ---------------------------------------------------------------------------
__global__ __launch_bounds__(256) void stage1(
    const float* __restrict__ labels,   // (B,10,128) fp32
    const float* __restrict__ theta,
    const short* __restrict__ w1n,      // (576,128) bf16, n=kk*64+oc
    const short* __restrict__ w2b,      // (32,576) bf16
    const int*   __restrict__ maxobj_p,
    float* __restrict__ h2pre,          // (B,32,4,4)
    float* __restrict__ bn2s, float* __restrict__ bn2s2)
{
    __shared__ __align__(16) unsigned char smem[32496];
    short* CPT  = (short*)(smem);             // [p=64][k stride 104]
    short* AT2  = (short*)(smem + 13312);     // [oc=64][k stride 104]
    short* LBF  = (short*)(smem + 26624);     // [m=16][c stride 136]
    short* H1T  = (short*)(smem);             // [pix=100][oc stride 66]
    short* H2C  = (short*)(smem + 13312);     // [p2=16][k2 stride 584]
    float* TH   = (float*)(smem + 32000);
    float* CS   = (float*)(smem + 32240);
    float* CS2  = (float*)(smem + 32368);

    const int b = blockIdx.x, t = threadIdx.x;
    const int w = t >> 6, l = t & 63, lm = l & 15, lq = l >> 4;
    const int nobj = min(maxobj_p[0], O_MAX);

    // ---- phase 0: LBF rows 0-9 from labels (bf16, stride 136), rows 10-15
    // zero; TH; zero CPT/AT2 columns k in [90,98) (MFMA K-pad, reads go to 95)
    for (int i = t; i < 320; i += 256) {             // 10 rows x 32 float4
        float4 v = *(const float4*)&labels[(size_t)b * 1280 + i * 4];
        const int row = i >> 5, c4 = i & 31;
        unsigned lo = f2bf(v.x) | ((unsigned)f2bf(v.y) << 16);
        unsigned hi = f2bf(v.z) | ((unsigned)f2bf(v.w) << 16);
        *(uint2*)&LBF[row * 136 + c4 * 4] = make_uint2(lo, hi);
    }
    for (int i = t; i < 384; i += 256) {             // rows 10-15 x 64 u32
        const int row = 10 + (i >> 6), cu = i & 63;
        *(unsigned*)&LBF[row * 136 + cu * 2] = 0u;
    }
    for (int i = t; i < 512; i += 256) {             // 64 rows x 8 k-tail
        const int p = i >> 3, kz = 90 + (i & 7);
        CPT[p * 104 + kz] = 0;
        AT2[p * 104 + kz] = 0;
    }
    if (t < 60) TH[t] = theta[b * 60 + t];
    __syncthreads();

    // ---- phase 1a: covpT[p][k=o*9+kk] computed directly (no COVf staging).
    // CPT[p][k] = coverage of object o at input pixel (2y+ky-1, 2x+kx-1),
    // zero outside the 16x16 image (conv zero-pad) or for o >= nobj.
    for (int i = t; i < 5760; i += 256) {            // 90 k x 64 p
        const int k = i >> 6, p = i & 63;            // k wave-uniform
        const int o = k / 9, kk = k - 9 * o;
        float val = 0.f;
        if (o < nobj) {
            const int ky = kk / 3, kx = kk - 3 * ky;
            const int py = 2 * (p >> 3) + ky - 1;    // -1..15
            const int px = 2 * (p & 7) + kx - 1;
            if (((unsigned)py < 16u) && ((unsigned)px < 16u)) {
                const float X = 0.125f * (float)px + (0.0625f - 1.f);
                const float Y = 0.125f * (float)py + (0.0625f - 1.f);
                const float* tt = &TH[o * 6];
                const float gx = tt[0] * X + tt[1] * Y + tt[2];
                const float gy = tt[3] * X + tt[4] * Y + tt[5];
                float ix = (gx + 1.f) * 8.f - 0.5f;
                float x0 = floorf(ix), fx = ix - x0;
                float cx = (1.f - fx) * ((x0 >= 0.f  && x0 <= 15.f) ? 1.f : 0.f)
                         +        fx  * ((x0 >= -1.f && x0 <= 14.f) ? 1.f : 0.f);
                float iy = (gy + 1.f) * 8.f - 0.5f;
                float y0 = floorf(iy), fy = iy - y0;
                float cy = (1.f - fy) * ((y0 >= 0.f  && y0 <= 15.f) ? 1.f : 0.f)
                         +        fy  * ((y0 >= -1.f && y0 <= 14.f) ? 1.f : 0.f);
                val = cx * cy;
            }
        }
        CPT[p * 104 + k] = (short)f2bf(val);
    }

    // ---- phase 1b: fused A-GEMM. wave w owns n in [w*144, w*144+144).
    // C[m=o][n=(kk,oc)] = sum_c LBF[m][c] * w1n[n][c]; scatter bf16 -> AT2.
    {
        const int n00 = w * 144;
        s8v afr[4];
        #pragma unroll
        for (int ks = 0; ks < 4; ++ks)
            afr[ks] = *(const s8v*)&LBF[lm * 136 + lq * 8 + ks * 32];
        #pragma unroll
        for (int nt = 0; nt < 9; ++nt) {
            const int n = n00 + nt * 16 + lm;
            const short* brow = w1n + (size_t)n * 128 + lq * 8;
            f4v acc = (f4v){0.f, 0.f, 0.f, 0.f};
            #pragma unroll
            for (int ks = 0; ks < 4; ++ks) {
                s8v bb = *(const s8v*)(brow + ks * 32);
                acc = MFMA(afr[ks], bb, acc);
            }
            const int kk = n >> 6, oc = n & 63;
            #pragma unroll
            for (int r = 0; r < 4; ++r) {
                const int m = lq * 4 + r;
                if (m < 10)
                    AT2[oc * 104 + m * 9 + kk] = (short)f2bf(acc[r]);
            }
        }
    }
    __syncthreads();

    // ---- phase 3: conv1 MFMA.  wave w -> oc tile [16w,16w+16); K=96
    f4v c1[4];
    #pragma unroll
    for (int nt = 0; nt < 4; ++nt) c1[nt] = (f4v){0.f, 0.f, 0.f, 0.f};
    {
        const short* at = AT2 + (16 * w + lm) * 104 + lq * 8;
        const short* cp = CPT + lm * 104 + lq * 8;
        #pragma unroll
        for (int ks = 0; ks < 3; ++ks) {
            s8v a = *(const s8v*)(at + ks * 32);
            #pragma unroll
            for (int nt = 0; nt < 4; ++nt) {
                s8v bb = *(const s8v*)(cp + nt * 1664 + ks * 32);
                c1[nt] = MFMA(a, bb, c1[nt]);
            }
        }
    }
    __syncthreads();   // covpT/AT2 reads done before H1T overlay writes

    // conv1 epilogue: zero H1T border rows, write lrelu(bf16) interior
    for (int i = t; i < 1188; i += 256) {           // 36 border rows x 33 u32
        const int j = i / 33, col = i - 33 * j;
        int r;
        if (j < 10) r = j;
        else if (j < 20) r = 90 + (j - 10);
        else { int jj = j - 20; r = 10 + (jj >> 1) * 10 + ((jj & 1) ? 9 : 0); }
        ((unsigned*)H1T)[r * 33 + col] = 0u;
    }
    #pragma unroll
    for (int nt = 0; nt < 4; ++nt) {
        const int p = nt * 16 + lm, y = p >> 3, x = p & 7;
        const int pix = (y + 1) * 10 + (x + 1);
        #pragma unroll
        for (int r = 0; r < 4; ++r) {
            const int oc = 16 * w + lq * 4 + r;
            float v = c1[nt][r];
            v = (v >= 0.f) ? v : SLOPE * v;
            H1T[pix * 66 + oc] = (short)f2bf(v);
        }
    }
    __syncthreads();

    // ---- phase 4: im2col pairs -> h2colT[p2][k2=tap*64+c] (stride 584)
    for (int i = t; i < 4608; i += 256) {
        const int p2 = i & 15, kp = i >> 4;         // kp = tap*32 + c2
        const int c2 = kp & 31, tap = kp >> 5;
        const int ky = (tap * 11) >> 5, kx = tap - 3 * ky;
        const int y2 = p2 >> 2, x2 = p2 & 3;
        const int pix = (2 * y2 + ky) * 10 + (2 * x2 + kx);
        const unsigned v = *(const unsigned*)&H1T[pix * 66 + 2 * c2];
        *(unsigned*)&H2C[p2 * 584 + tap * 64 + 2 * c2] = v;
    }
    __syncthreads();

    // ---- phase 5: conv2 MFMA, full K=576 on waves 0,1 (mi = w); no SCR
    if (w < 2) {
        f4v c2 = (f4v){0.f, 0.f, 0.f, 0.f};
        const short* wrow = w2b + (size_t)(w * 16 + lm) * 576 + lq * 8;
        const short* hrow = H2C + lm * 584 + lq * 8;
        #pragma unroll
        for (int ks = 0; ks < 18; ++ks) {
            s8v a  = *(const s8v*)(wrow + ks * 32);
            s8v bb = *(const s8v*)(hrow + ks * 32);
            c2 = MFMA(a, bb, c2);
        }
        #pragma unroll
        for (int r = 0; r < 4; ++r) {
            const int oc = w * 16 + lq * 4 + r;
            float v = c2[r];
            h2pre[(size_t)b * 512 + oc * 16 + lm] = v;
            float s1 = v, s2 = v * v;
            #pragma unroll
            for (int m = 1; m < 16; m <<= 1) {
                s1 += __shfl_xor(s1, m, 16);
                s2 += __shfl_xor(s2, m, 16);
            }
            if (lm == 0) { CS[oc] = s1; CS2[oc] = s2; }
        }
    }
    __syncthreads();
    if (t < 32) {
        atomicAdd(&bn2s[t],  CS[t]);
        atomicAdd(&bn2s2[t], CS2[t]);
    }
}

// ---------------------------------------------------------------------------
// stage2: 4 b per block. BN2+lrelu, conv3, BN3 sums
// ---------------------------------------------------------------------------
__global__ __launch_bounds__(256) void stage2(
    const float* __restrict__ h2pre,
    const float* __restrict__ gamma2, const float* __restrict__ beta2,
    const float* __restrict__ w3,
    const float* __restrict__ bn2s, const float* __restrict__ bn2s2,
    float* __restrict__ h3pre,
    float* __restrict__ bn3s, float* __restrict__ bn3s2, int B)
{
    const int b0 = blockIdx.x * 4, t = threadIdx.x;
    __shared__ float s_scale[32], s_shift[32];
    __shared__ float s_pad[4 * 32 * 36];
    __shared__ float s_c3[16], s_c32[16];

    if (t < 32) {
        const float n = (float)B * 16.f;
        const float mean = bn2s[t] / n;
        const float var  = bn2s2[t] / n - mean * mean;
        const float sc   = gamma2[t] * rsqrtf(var + BN_EPS);
        s_scale[t] = sc;
        s_shift[t] = beta2[t] - mean * sc;
    }
    if (t < 16) { s_c3[t] = 0.f; s_c32[t] = 0.f; }
    for (int i = t; i < 4 * 32 * 36; i += 256) s_pad[i] = 0.f;
    __syncthreads();

    for (int i = t; i < 2048; i += 256) {
        const int lb = i >> 9, r = i & 511;
        const int c = r >> 4, p = r & 15, y = p >> 2, x = p & 3;
        const float v = h2pre[(size_t)b0 * 512 + i] * s_scale[c] + s_shift[c];
        const float a = (v >= 0.f) ? v : SLOPE * v;
        s_pad[lb * 1152 + c * 36 + (y + 1) * 6 + (x + 1)] = a;
    }
    __syncthreads();

    {
        const int lb = t >> 6, r = t & 63;
        const int oc = r >> 2, p = r & 3, y = p >> 1, x = p & 1;
        float acc = 0.f;
        const float* wp = w3 + oc * 288;
        const float* hp = &s_pad[lb * 1152];
        for (int c = 0; c < 32; ++c) {
            const float* hc = hp + c * 36;
            #pragma unroll
            for (int ky = 0; ky < 3; ++ky)
                #pragma unroll
                for (int kx = 0; kx < 3; ++kx)
                    acc += wp[c * 9 + ky * 3 + kx] * hc[(2 * y + ky) * 6 + (2 * x + kx)];
        }
        h3pre[(size_t)b0 * 64 + t] = acc;
        atomicAdd(&s_c3[oc],  acc);
        atomicAdd(&s_c32[oc], acc * acc);
    }
    __syncthreads();
    if (t < 16) {
        atomicAdd(&bn3s[t],  s_c3[t]);
        atomicAdd(&bn3s2[t], s_c32[t]);
    }
}

// ---------------------------------------------------------------------------
// stage3: BN3 + lrelu -> out
// ---------------------------------------------------------------------------
__global__ __launch_bounds__(256) void stage3(
    const float* __restrict__ h3pre,
    const float* __restrict__ gamma3, const float* __restrict__ beta3,
    const float* __restrict__ bn3s, const float* __restrict__ bn3s2,
    float* __restrict__ out, int total, int B)
{
    __shared__ float s_scale[16], s_shift[16];
    if (threadIdx.x < 16) {
        const int c = threadIdx.x;
        const float n = (float)B * 4.f;
        const float mean = bn3s[c] / n;
        const float var  = bn3s2[c] / n - mean * mean;
        const float sc   = gamma3[c] * rsqrtf(var + BN_EPS);
        s_scale[c] = sc;
        s_shift[c] = beta3[c] - mean * sc;
    }
    __syncthreads();
    const int idx = blockIdx.x * 256 + threadIdx.x;
    if (idx < total) {
        const int c = (idx & 63) >> 2;
        const float v = h3pre[idx] * s_scale[c] + s_shift[c];
        out[idx] = (v >= 0.f) ? v : SLOPE * v;
    }
}

extern "C" void kernel_launch(void* const* d_in, const int* in_sizes, int n_in,
                              void* d_out, int out_size, void* d_ws, size_t ws_size,
                              hipStream_t stream)
{
    const float* labels = (const float*)d_in[0];
    const float* theta  = (const float*)d_in[1];
    const float* w1     = (const float*)d_in[2];
    const float* w2     = (const float*)d_in[3];
    const float* gamma2 = (const float*)d_in[4];
    const float* beta2  = (const float*)d_in[5];
    const float* w3     = (const float*)d_in[6];
    const float* gamma3 = (const float*)d_in[7];
    const float* beta3  = (const float*)d_in[8];
    const int*   maxobj = (const int*)d_in[9];

    const int B = in_sizes[0] / (O_MAX * C_DIM);   // 2048

    unsigned char* ws = (unsigned char*)d_ws;
    float* h2pre = (float*)ws;                                  // B*512 f32
    float* h3pre = h2pre + (size_t)B * 512;                     // B*64
    float* sums  = h3pre + (size_t)B * 64;                      // 96
    short* w1n   = (short*)(sums + 96);                         // 73728 sh
    short* w2b   = w1n + N_W1N;                                 // 18432 sh
    float* bn2s  = sums;
    float* bn2s2 = sums + 32;
    float* bn3s  = sums + 64;
    float* bn3s2 = sums + 80;

    const int prep_total = N_W1N + N_W2B + 96;
    prep<<<(prep_total + 255) / 256, 256, 0, stream>>>(w1, w2, w1n, w2b, sums);
    stage1<<<B, 256, 0, stream>>>(labels, theta, w1n, w2b, maxobj,
                                  h2pre, bn2s, bn2s2);
    stage2<<<B / 4, 256, 0, stream>>>(h2pre, gamma2, beta2, w3, bn2s, bn2s2,
                                      h3pre, bn3s, bn3s2, B);
    const int total = B * 64;
    stage3<<<(total + 255) / 256, 256, 0, stream>>>(h3pre, gamma3, beta3,
                                                    bn3s, bn3s2, (float*)d_out,
                                                    total, B);
}

// Round 4
// 168.212 us; speedup vs baseline: 1.0926x; 1.0275x over previous
//
#include <hip/hip_runtime.h>

#define C_DIM   128
#define O_MAX   10
#define BN_EPS  1e-5f
#define SLOPE   0.2f

typedef short s8v  __attribute__((ext_vector_type(8)));   // 8 bf16 (4 VGPRs)
typedef float f4v  __attribute__((ext_vector_type(4)));   // MFMA accumulator
#define MFMA(a,b,c) __builtin_amdgcn_mfma_f32_16x16x32_bf16(a,b,c,0,0,0)

__device__ inline unsigned short f2bf(float f) {          // RNE fp32->bf16
    unsigned u = __float_as_uint(f);
    unsigned r = u + 0x7FFFu + ((u >> 16) & 1u);
    return (unsigned short)(r >> 16);
}

// ---------------------------------------------------------------------------
// prep: w1n[n=(kk,oc)][c=128] bf16 ; w2b[oc][k2=tap*64+c] bf16 (tight 576) ;
// zero BN sums.
// ---------------------------------------------------------------------------
#define N_W1N  73728
#define N_W2B  18432       /* 32*576 */
__global__ __launch_bounds__(256) void prep(
    const float* __restrict__ w1, const float* __restrict__ w2,
    short* __restrict__ w1n, short* __restrict__ w2b,
    float* __restrict__ sums)
{
    int i = blockIdx.x * 256 + threadIdx.x;
    if (i < N_W1N) {                       // w1n[n][c] = w1[oc][c][kk], n=kk*64+oc
        int n = i >> 7, c = i & 127;
        int kk = n >> 6, oc = n & 63;
        w1n[i] = f2bf(w1[oc * 1152 + c * 9 + kk]);
        return;
    }
    i -= N_W1N;
    if (i < N_W2B) {                       // w2b[oc][k2], k2 = tap*64+c
        int oc = i / 576, k2 = i % 576;
        int tap = k2 >> 6, c = k2 & 63;
        w2b[i] = f2bf(w2[oc * 576 + c * 9 + tap]);
        return;
    }
    i -= N_W2B;
    if (i < 96) sums[i] = 0.f;
}

// ---------------------------------------------------------------------------
// stage1 (per-b block, 256 thr, LDS-limited 5 blocks/CU):
//   phase0: LBF bf16 (stride 136), TH, zero tails
//   phase1: prefetch w1n rows -> CPT direct from theta -> pipelined A-GEMM
//   phase3: conv1 MFMA -> lrelu -> H1T (stride 72, 16B-aligned rows)
//   phase5: conv2 MFMA reads H1T DIRECTLY (no im2col/H2C) on waves 0,1 ; BN2.
// LDS (bytes): CPT 0..13312 | AT2 13312..26624 | LBF 26624..30976 |
//   TH 30976..31216 | CS 31216..31344 | CS2 31344..31472
// overlay (CPT/AT2 dead after conv1): H1T 0..14400  (100 pix x 72 sh)
// total 31472 -> <= 32 KiB -> 5 blocks/CU
// ---------------------------------------------------------------------------
__global__ __launch_bounds__(256) void stage1(
    const float* __restrict__ labels,   // (B,10,128) fp32
    const float* __restrict__ theta,
    const short* __restrict__ w1n,      // (576,128) bf16, n=kk*64+oc
    const short* __restrict__ w2b,      // (32,576) bf16
    const int*   __restrict__ maxobj_p,
    float* __restrict__ h2pre,          // (B,32,4,4)
    float* __restrict__ bn2s, float* __restrict__ bn2s2)
{
    __shared__ __align__(16) unsigned char smem[31472];
    short* CPT  = (short*)(smem);             // [p=64][k stride 104]
    short* AT2  = (short*)(smem + 13312);     // [oc=64][k stride 104]
    short* LBF  = (short*)(smem + 26624);     // [m=16][c stride 136]
    short* H1T  = (short*)(smem);             // [pix=100][oc stride 72]
    float* TH   = (float*)(smem + 30976);
    float* CS   = (float*)(smem + 31216);
    float* CS2  = (float*)(smem + 31344);

    const int b = blockIdx.x, t = threadIdx.x;
    const int w = t >> 6, l = t & 63, lm = l & 15, lq = l >> 4;
    const int nobj = min(maxobj_p[0], O_MAX);

    // ---- phase 0: LBF rows 0-9 from labels (bf16, stride 136), rows 10-15
    // zero; TH; zero CPT/AT2 columns k in [90,98) (MFMA K-pad, reads go to 95)
    for (int i = t; i < 320; i += 256) {             // 10 rows x 32 float4
        float4 v = *(const float4*)&labels[(size_t)b * 1280 + i * 4];
        const int row = i >> 5, c4 = i & 31;
        unsigned lo = f2bf(v.x) | ((unsigned)f2bf(v.y) << 16);
        unsigned hi = f2bf(v.z) | ((unsigned)f2bf(v.w) << 16);
        *(uint2*)&LBF[row * 136 + c4 * 4] = make_uint2(lo, hi);
    }
    for (int i = t; i < 384; i += 256) {             // rows 10-15 x 64 u32
        const int row = 10 + (i >> 6), cu = i & 63;
        *(unsigned*)&LBF[row * 136 + cu * 2] = 0u;
    }
    for (int i = t; i < 512; i += 256) {             // 64 rows x 8 k-tail
        const int p = i >> 3, kz = 90 + (i & 7);
        CPT[p * 104 + kz] = 0;
        AT2[p * 104 + kz] = 0;
    }
    if (t < 60) TH[t] = theta[b * 60 + t];
    __syncthreads();

    // ---- phase 1: prefetch A-GEMM operands FIRST (global loads fly under
    // the CPT VALU burst), then CPT compute, then pipelined A-GEMM.
    s8v afr[4];
    #pragma unroll
    for (int ks = 0; ks < 4; ++ks)
        afr[ks] = *(const s8v*)&LBF[lm * 136 + lq * 8 + ks * 32];
    const short* brow_base = w1n + (size_t)(w * 144 + lm) * 128 + lq * 8;
    s8v bcur[4], bnxt[4];
    #pragma unroll
    for (int ks = 0; ks < 4; ++ks)
        bcur[ks] = *(const s8v*)(brow_base + ks * 32);
    #pragma unroll
    for (int ks = 0; ks < 4; ++ks)
        bnxt[ks] = *(const s8v*)(brow_base + 16 * 128 + ks * 32);

    // ---- phase 1a: covpT[p][k=o*9+kk] computed directly from theta.
    for (int i = t; i < 5760; i += 256) {            // 90 k x 64 p
        const int k = i >> 6, p = i & 63;            // k wave-uniform
        const int o = k / 9, kk = k - 9 * o;
        float val = 0.f;
        if (o < nobj) {
            const int ky = kk / 3, kx = kk - 3 * ky;
            const int py = 2 * (p >> 3) + ky - 1;    // -1..15
            const int px = 2 * (p & 7) + kx - 1;
            if (((unsigned)py < 16u) && ((unsigned)px < 16u)) {
                const float X = 0.125f * (float)px + (0.0625f - 1.f);
                const float Y = 0.125f * (float)py + (0.0625f - 1.f);
                const float* tt = &TH[o * 6];
                const float gx = tt[0] * X + tt[1] * Y + tt[2];
                const float gy = tt[3] * X + tt[4] * Y + tt[5];
                float ix = (gx + 1.f) * 8.f - 0.5f;
                float x0 = floorf(ix), fx = ix - x0;
                float cx = (1.f - fx) * ((x0 >= 0.f  && x0 <= 15.f) ? 1.f : 0.f)
                         +        fx  * ((x0 >= -1.f && x0 <= 14.f) ? 1.f : 0.f);
                float iy = (gy + 1.f) * 8.f - 0.5f;
                float y0 = floorf(iy), fy = iy - y0;
                float cy = (1.f - fy) * ((y0 >= 0.f  && y0 <= 15.f) ? 1.f : 0.f)
                         +        fy  * ((y0 >= -1.f && y0 <= 14.f) ? 1.f : 0.f);
                val = cx * cy;
            }
        }
        CPT[p * 104 + k] = (short)f2bf(val);
    }

    // ---- phase 1b: pipelined A-GEMM. wave w owns n in [w*144, w*144+144).
    // C[m=o][n=(kk,oc)] = sum_c LBF[m][c] * w1n[n][c]; scatter bf16 -> AT2.
    #pragma unroll
    for (int nt = 0; nt < 9; ++nt) {
        f4v acc = (f4v){0.f, 0.f, 0.f, 0.f};
        #pragma unroll
        for (int ks = 0; ks < 4; ++ks)
            acc = MFMA(afr[ks], bcur[ks], acc);
        #pragma unroll
        for (int ks = 0; ks < 4; ++ks) bcur[ks] = bnxt[ks];
        if (nt < 7) {
            #pragma unroll
            for (int ks = 0; ks < 4; ++ks)
                bnxt[ks] = *(const s8v*)(brow_base + (size_t)(nt + 2) * 16 * 128 + ks * 32);
        }
        const int n = w * 144 + nt * 16 + lm;
        const int kk = n >> 6, oc = n & 63;
        #pragma unroll
        for (int r = 0; r < 4; ++r) {
            const int m = lq * 4 + r;
            if (m < 10)
                AT2[oc * 104 + m * 9 + kk] = (short)f2bf(acc[r]);
        }
    }
    __syncthreads();

    // ---- phase 3: conv1 MFMA.  wave w -> oc tile [16w,16w+16); K=96
    f4v c1[4];
    #pragma unroll
    for (int nt = 0; nt < 4; ++nt) c1[nt] = (f4v){0.f, 0.f, 0.f, 0.f};
    {
        const short* at = AT2 + (16 * w + lm) * 104 + lq * 8;
        const short* cp = CPT + lm * 104 + lq * 8;
        #pragma unroll
        for (int ks = 0; ks < 3; ++ks) {
            s8v a = *(const s8v*)(at + ks * 32);
            #pragma unroll
            for (int nt = 0; nt < 4; ++nt) {
                s8v bb = *(const s8v*)(cp + nt * 1664 + ks * 32);
                c1[nt] = MFMA(a, bb, c1[nt]);
            }
        }
    }
    __syncthreads();   // CPT/AT2 reads done before H1T overlay writes

    // conv1 epilogue: zero H1T border pixel rows, write lrelu(bf16) interior
    for (int i = t; i < 1152; i += 256) {           // 36 border pix x 32 u32
        const int j = i >> 5, col = i & 31;
        int r;
        if (j < 10) r = j;
        else if (j < 20) r = 90 + (j - 10);
        else { int jj = j - 20; r = 10 + (jj >> 1) * 10 + ((jj & 1) ? 9 : 0); }
        ((unsigned*)H1T)[r * 36 + col] = 0u;
    }
    #pragma unroll
    for (int nt = 0; nt < 4; ++nt) {
        const int p = nt * 16 + lm, y = p >> 3, x = p & 7;
        const int pix = (y + 1) * 10 + (x + 1);
        #pragma unroll
        for (int r = 0; r < 4; ++r) {
            const int oc = 16 * w + lq * 4 + r;
            float v = c1[nt][r];
            v = (v >= 0.f) ? v : SLOPE * v;
            H1T[pix * 72 + oc] = (short)f2bf(v);
        }
    }

    // prefetch conv2 A-operand (global, independent of H1T) before barrier
    s8v wa0, wa1;
    const short* wrow = w2b + (size_t)((w & 1) * 16 + lm) * 576 + lq * 8;
    if (w < 2) {
        wa0 = *(const s8v*)(wrow);
        wa1 = *(const s8v*)(wrow + 32);
    }
    __syncthreads();

    // ---- phase 5: conv2 MFMA, full K=576 on waves 0,1; B read from H1T
    // directly: B[p2][k2=tap*64+c] = H1T[pix(tap,p2)*72 + c]
    if (w < 2) {
        f4v c2 = (f4v){0.f, 0.f, 0.f, 0.f};
        const short* hbase = H1T + (20 * (lm >> 2) + 2 * (lm & 3)) * 72 + lq * 8;
        #pragma unroll
        for (int ks = 0; ks < 18; ++ks) {
            const int tap = ks >> 1;
            const int ky = tap / 3, kx = tap - 3 * ky;       // compile-time
            s8v a = (ks == 0) ? wa0 : (ks == 1) ? wa1
                  : *(const s8v*)(wrow + ks * 32);
            s8v bb = *(const s8v*)(hbase + (ky * 10 + kx) * 72 + (ks & 1) * 32);
            c2 = MFMA(a, bb, c2);
        }
        #pragma unroll
        for (int r = 0; r < 4; ++r) {
            const int oc = w * 16 + lq * 4 + r;
            float v = c2[r];
            h2pre[(size_t)b * 512 + oc * 16 + lm] = v;
            float s1 = v, s2 = v * v;
            #pragma unroll
            for (int m = 1; m < 16; m <<= 1) {
                s1 += __shfl_xor(s1, m, 16);
                s2 += __shfl_xor(s2, m, 16);
            }
            if (lm == 0) { CS[oc] = s1; CS2[oc] = s2; }
        }
    }
    __syncthreads();
    if (t < 32) {
        atomicAdd(&bn2s[t],  CS[t]);
        atomicAdd(&bn2s2[t], CS2[t]);
    }
}

// ---------------------------------------------------------------------------
// stage2: 4 b per block. BN2+lrelu, conv3, BN3 sums
// ---------------------------------------------------------------------------
__global__ __launch_bounds__(256) void stage2(
    const float* __restrict__ h2pre,
    const float* __restrict__ gamma2, const float* __restrict__ beta2,
    const float* __restrict__ w3,
    const float* __restrict__ bn2s, const float* __restrict__ bn2s2,
    float* __restrict__ h3pre,
    float* __restrict__ bn3s, float* __restrict__ bn3s2, int B)
{
    const int b0 = blockIdx.x * 4, t = threadIdx.x;
    __shared__ float s_scale[32], s_shift[32];
    __shared__ float s_pad[4 * 32 * 36];
    __shared__ float s_c3[16], s_c32[16];

    if (t < 32) {
        const float n = (float)B * 16.f;
        const float mean = bn2s[t] / n;
        const float var  = bn2s2[t] / n - mean * mean;
        const float sc   = gamma2[t] * rsqrtf(var + BN_EPS);
        s_scale[t] = sc;
        s_shift[t] = beta2[t] - mean * sc;
    }
    if (t < 16) { s_c3[t] = 0.f; s_c32[t] = 0.f; }
    for (int i = t; i < 4 * 32 * 36; i += 256) s_pad[i] = 0.f;
    __syncthreads();

    for (int i = t; i < 2048; i += 256) {
        const int lb = i >> 9, r = i & 511;
        const int c = r >> 4, p = r & 15, y = p >> 2, x = p & 3;
        const float v = h2pre[(size_t)b0 * 512 + i] * s_scale[c] + s_shift[c];
        const float a = (v >= 0.f) ? v : SLOPE * v;
        s_pad[lb * 1152 + c * 36 + (y + 1) * 6 + (x + 1)] = a;
    }
    __syncthreads();

    {
        const int lb = t >> 6, r = t & 63;
        const int oc = r >> 2, p = r & 3, y = p >> 1, x = p & 1;
        float acc = 0.f;
        const float* wp = w3 + oc * 288;
        const float* hp = &s_pad[lb * 1152];
        for (int c = 0; c < 32; ++c) {
            const float* hc = hp + c * 36;
            #pragma unroll
            for (int ky = 0; ky < 3; ++ky)
                #pragma unroll
                for (int kx = 0; kx < 3; ++kx)
                    acc += wp[c * 9 + ky * 3 + kx] * hc[(2 * y + ky) * 6 + (2 * x + kx)];
        }
        h3pre[(size_t)b0 * 64 + t] = acc;
        atomicAdd(&s_c3[oc],  acc);
        atomicAdd(&s_c32[oc], acc * acc);
    }
    __syncthreads();
    if (t < 16) {
        atomicAdd(&bn3s[t],  s_c3[t]);
        atomicAdd(&bn3s2[t], s_c32[t]);
    }
}

// ---------------------------------------------------------------------------
// stage3: BN3 + lrelu -> out
// ---------------------------------------------------------------------------
__global__ __launch_bounds__(256) void stage3(
    const float* __restrict__ h3pre,
    const float* __restrict__ gamma3, const float* __restrict__ beta3,
    const float* __restrict__ bn3s, const float* __restrict__ bn3s2,
    float* __restrict__ out, int total, int B)
{
    __shared__ float s_scale[16], s_shift[16];
    if (threadIdx.x < 16) {
        const int c = threadIdx.x;
        const float n = (float)B * 4.f;
        const float mean = bn3s[c] / n;
        const float var  = bn3s2[c] / n - mean * mean;
        const float sc   = gamma3[c] * rsqrtf(var + BN_EPS);
        s_scale[c] = sc;
        s_shift[c] = beta3[c] - mean * sc;
    }
    __syncthreads();
    const int idx = blockIdx.x * 256 + threadIdx.x;
    if (idx < total) {
        const int c = (idx & 63) >> 2;
        const float v = h3pre[idx] * s_scale[c] + s_shift[c];
        out[idx] = (v >= 0.f) ? v : SLOPE * v;
    }
}

extern "C" void kernel_launch(void* const* d_in, const int* in_sizes, int n_in,
                              void* d_out, int out_size, void* d_ws, size_t ws_size,
                              hipStream_t stream)
{
    const float* labels = (const float*)d_in[0];
    const float* theta  = (const float*)d_in[1];
    const float* w1     = (const float*)d_in[2];
    const float* w2     = (const float*)d_in[3];
    const float* gamma2 = (const float*)d_in[4];
    const float* beta2  = (const float*)d_in[5];
    const float* w3     = (const float*)d_in[6];
    const float* gamma3 = (const float*)d_in[7];
    const float* beta3  = (const float*)d_in[8];
    const int*   maxobj = (const int*)d_in[9];

    const int B = in_sizes[0] / (O_MAX * C_DIM);   // 2048

    unsigned char* ws = (unsigned char*)d_ws;
    float* h2pre = (float*)ws;                                  // B*512 f32
    float* h3pre = h2pre + (size_t)B * 512;                     // B*64
    float* sums  = h3pre + (size_t)B * 64;                      // 96
    short* w1n   = (short*)(sums + 96);                         // 73728 sh
    short* w2b   = w1n + N_W1N;                                 // 18432 sh
    float* bn2s  = sums;
    float* bn2s2 = sums + 32;
    float* bn3s  = sums + 64;
    float* bn3s2 = sums + 80;

    const int prep_total = N_W1N + N_W2B + 96;
    prep<<<(prep_total + 255) / 256, 256, 0, stream>>>(w1, w2, w1n, w2b, sums);
    stage1<<<B, 256, 0, stream>>>(labels, theta, w1n, w2b, maxobj,
                                  h2pre, bn2s, bn2s2);
    stage2<<<B / 4, 256, 0, stream>>>(h2pre, gamma2, beta2, w3, bn2s, bn2s2,
                                      h3pre, bn3s, bn3s2, B);
    const int total = B * 64;
    stage3<<<(total + 255) / 256, 256, 0, stream>>>(h3pre, gamma3, beta3,
                                                    bn3s, bn3s2, (float*)d_out,
                                                    total, B);
}

// Round 5
// 137.918 us; speedup vs baseline: 1.3325x; 1.2197x over previous
//
#include <hip/hip_runtime.h>

#define C_DIM   128
#define O_MAX   10
#define BN_EPS  1e-5f
#define SLOPE   0.2f

typedef short s8v  __attribute__((ext_vector_type(8)));   // 8 bf16 (4 VGPRs)
typedef float f4v  __attribute__((ext_vector_type(4)));   // MFMA accumulator
#define MFMA(a,b,c) __builtin_amdgcn_mfma_f32_16x16x32_bf16(a,b,c,0,0,0)

__device__ inline unsigned short f2bf(float f) {          // RNE fp32->bf16
    unsigned u = __float_as_uint(f);
    unsigned r = u + 0x7FFFu + ((u >> 16) & 1u);
    return (unsigned short)(r >> 16);
}

// ---------------------------------------------------------------------------
// prep: w1n[n=(kk,oc)][c=128] bf16 ; w2b[oc][k2=tap*64+c] bf16 (tight 576) ;
// zero replicated BN sum buffers (bn2r 64x64 + bn3r 32x32 = 5120 floats).
// ---------------------------------------------------------------------------
#define N_W1N  73728
#define N_W2B  18432       /* 32*576 */
#define N_SUMS 5120        /* 64*64 bn2r + 32*32 bn3r */
__global__ __launch_bounds__(256) void prep(
    const float* __restrict__ w1, const float* __restrict__ w2,
    short* __restrict__ w1n, short* __restrict__ w2b,
    float* __restrict__ sums)
{
    int i = blockIdx.x * 256 + threadIdx.x;
    if (i < N_W1N) {                       // w1n[n][c] = w1[oc][c][kk], n=kk*64+oc
        int n = i >> 7, c = i & 127;
        int kk = n >> 6, oc = n & 63;
        w1n[i] = f2bf(w1[oc * 1152 + c * 9 + kk]);
        return;
    }
    i -= N_W1N;
    if (i < N_W2B) {                       // w2b[oc][k2], k2 = tap*64+c
        int oc = i / 576, k2 = i % 576;
        int tap = k2 >> 6, c = k2 & 63;
        w2b[i] = f2bf(w2[oc * 576 + c * 9 + tap]);
        return;
    }
    i -= N_W2B;
    if (i < N_SUMS) sums[i] = 0.f;
}

// ---------------------------------------------------------------------------
// stage1 (per-b block, 256 thr, LDS-limited 5 blocks/CU):
//   phase0: LBF bf16 (stride 136), TH, zero tails
//   phase1: prefetch w1n rows -> CPT direct from theta -> pipelined A-GEMM
//   phase3: conv1 MFMA -> lrelu -> H1T (stride 72, 16B-aligned rows)
//   phase5: conv2 MFMA reads H1T directly on waves 0,1 ; BN2 partial ->
//           REPLICATED atomic buffer bn2r[b&63][64] (kills same-address
//           contention: 2048 -> 32 RMWs per address).
// LDS (bytes): CPT 0..13312 | AT2 13312..26624 | LBF 26624..30976 |
//   TH 30976..31216 | CS 31216..31344 | CS2 31344..31472
// overlay (CPT/AT2 dead after conv1): H1T 0..14400  (100 pix x 72 sh)
// total 31472 -> <= 32 KiB -> 5 blocks/CU
// ---------------------------------------------------------------------------
__global__ __launch_bounds__(256) void stage1(
    const float* __restrict__ labels,   // (B,10,128) fp32
    const float* __restrict__ theta,
    const short* __restrict__ w1n,      // (576,128) bf16, n=kk*64+oc
    const short* __restrict__ w2b,      // (32,576) bf16
    const int*   __restrict__ maxobj_p,
    float* __restrict__ h2pre,          // (B,32,4,4)
    float* __restrict__ bn2r)           // (64 reps, 64) s1[0:32] s2[32:64]
{
    __shared__ __align__(16) unsigned char smem[31472];
    short* CPT  = (short*)(smem);             // [p=64][k stride 104]
    short* AT2  = (short*)(smem + 13312);     // [oc=64][k stride 104]
    short* LBF  = (short*)(smem + 26624);     // [m=16][c stride 136]
    short* H1T  = (short*)(smem);             // [pix=100][oc stride 72]
    float* TH   = (float*)(smem + 30976);
    float* CS   = (float*)(smem + 31216);
    float* CS2  = (float*)(smem + 31344);

    const int b = blockIdx.x, t = threadIdx.x;
    const int w = t >> 6, l = t & 63, lm = l & 15, lq = l >> 4;
    const int nobj = min(maxobj_p[0], O_MAX);

    // ---- phase 0: LBF rows 0-9 from labels (bf16, stride 136), rows 10-15
    // zero; TH; zero CPT/AT2 columns k in [90,98) (MFMA K-pad, reads go to 95)
    for (int i = t; i < 320; i += 256) {             // 10 rows x 32 float4
        float4 v = *(const float4*)&labels[(size_t)b * 1280 + i * 4];
        const int row = i >> 5, c4 = i & 31;
        unsigned lo = f2bf(v.x) | ((unsigned)f2bf(v.y) << 16);
        unsigned hi = f2bf(v.z) | ((unsigned)f2bf(v.w) << 16);
        *(uint2*)&LBF[row * 136 + c4 * 4] = make_uint2(lo, hi);
    }
    for (int i = t; i < 384; i += 256) {             // rows 10-15 x 64 u32
        const int row = 10 + (i >> 6), cu = i & 63;
        *(unsigned*)&LBF[row * 136 + cu * 2] = 0u;
    }
    for (int i = t; i < 512; i += 256) {             // 64 rows x 8 k-tail
        const int p = i >> 3, kz = 90 + (i & 7);
        CPT[p * 104 + kz] = 0;
        AT2[p * 104 + kz] = 0;
    }
    if (t < 60) TH[t] = theta[b * 60 + t];
    __syncthreads();

    // ---- phase 1: prefetch A-GEMM operands FIRST (global loads fly under
    // the CPT VALU burst), then CPT compute, then pipelined A-GEMM.
    s8v afr[4];
    #pragma unroll
    for (int ks = 0; ks < 4; ++ks)
        afr[ks] = *(const s8v*)&LBF[lm * 136 + lq * 8 + ks * 32];
    const short* brow_base = w1n + (size_t)(w * 144 + lm) * 128 + lq * 8;
    s8v bcur[4], bnxt[4];
    #pragma unroll
    for (int ks = 0; ks < 4; ++ks)
        bcur[ks] = *(const s8v*)(brow_base + ks * 32);
    #pragma unroll
    for (int ks = 0; ks < 4; ++ks)
        bnxt[ks] = *(const s8v*)(brow_base + 16 * 128 + ks * 32);

    // ---- phase 1a: covpT[p][k=o*9+kk] computed directly from theta.
    for (int i = t; i < 5760; i += 256) {            // 90 k x 64 p
        const int k = i >> 6, p = i & 63;            // k wave-uniform
        const int o = k / 9, kk = k - 9 * o;
        float val = 0.f;
        if (o < nobj) {
            const int ky = kk / 3, kx = kk - 3 * ky;
            const int py = 2 * (p >> 3) + ky - 1;    // -1..15
            const int px = 2 * (p & 7) + kx - 1;
            if (((unsigned)py < 16u) && ((unsigned)px < 16u)) {
                const float X = 0.125f * (float)px + (0.0625f - 1.f);
                const float Y = 0.125f * (float)py + (0.0625f - 1.f);
                const float* tt = &TH[o * 6];
                const float gx = tt[0] * X + tt[1] * Y + tt[2];
                const float gy = tt[3] * X + tt[4] * Y + tt[5];
                float ix = (gx + 1.f) * 8.f - 0.5f;
                float x0 = floorf(ix), fx = ix - x0;
                float cx = (1.f - fx) * ((x0 >= 0.f  && x0 <= 15.f) ? 1.f : 0.f)
                         +        fx  * ((x0 >= -1.f && x0 <= 14.f) ? 1.f : 0.f);
                float iy = (gy + 1.f) * 8.f - 0.5f;
                float y0 = floorf(iy), fy = iy - y0;
                float cy = (1.f - fy) * ((y0 >= 0.f  && y0 <= 15.f) ? 1.f : 0.f)
                         +        fy  * ((y0 >= -1.f && y0 <= 14.f) ? 1.f : 0.f);
                val = cx * cy;
            }
        }
        CPT[p * 104 + k] = (short)f2bf(val);
    }

    // ---- phase 1b: pipelined A-GEMM. wave w owns n in [w*144, w*144+144).
    // C[m=o][n=(kk,oc)] = sum_c LBF[m][c] * w1n[n][c]; scatter bf16 -> AT2.
    #pragma unroll
    for (int nt = 0; nt < 9; ++nt) {
        f4v acc = (f4v){0.f, 0.f, 0.f, 0.f};
        #pragma unroll
        for (int ks = 0; ks < 4; ++ks)
            acc = MFMA(afr[ks], bcur[ks], acc);
        #pragma unroll
        for (int ks = 0; ks < 4; ++ks) bcur[ks] = bnxt[ks];
        if (nt < 7) {
            #pragma unroll
            for (int ks = 0; ks < 4; ++ks)
                bnxt[ks] = *(const s8v*)(brow_base + (size_t)(nt + 2) * 16 * 128 + ks * 32);
        }
        const int n = w * 144 + nt * 16 + lm;
        const int kk = n >> 6, oc = n & 63;
        #pragma unroll
        for (int r = 0; r < 4; ++r) {
            const int m = lq * 4 + r;
            if (m < 10)
                AT2[oc * 104 + m * 9 + kk] = (short)f2bf(acc[r]);
        }
    }
    __syncthreads();

    // ---- phase 3: conv1 MFMA.  wave w -> oc tile [16w,16w+16); K=96
    f4v c1[4];
    #pragma unroll
    for (int nt = 0; nt < 4; ++nt) c1[nt] = (f4v){0.f, 0.f, 0.f, 0.f};
    {
        const short* at = AT2 + (16 * w + lm) * 104 + lq * 8;
        const short* cp = CPT + lm * 104 + lq * 8;
        #pragma unroll
        for (int ks = 0; ks < 3; ++ks) {
            s8v a = *(const s8v*)(at + ks * 32);
            #pragma unroll
            for (int nt = 0; nt < 4; ++nt) {
                s8v bb = *(const s8v*)(cp + nt * 1664 + ks * 32);
                c1[nt] = MFMA(a, bb, c1[nt]);
            }
        }
    }
    __syncthreads();   // CPT/AT2 reads done before H1T overlay writes

    // conv1 epilogue: zero H1T border pixel rows, write lrelu(bf16) interior
    for (int i = t; i < 1152; i += 256) {           // 36 border pix x 32 u32
        const int j = i >> 5, col = i & 31;
        int r;
        if (j < 10) r = j;
        else if (j < 20) r = 90 + (j - 10);
        else { int jj = j - 20; r = 10 + (jj >> 1) * 10 + ((jj & 1) ? 9 : 0); }
        ((unsigned*)H1T)[r * 36 + col] = 0u;
    }
    #pragma unroll
    for (int nt = 0; nt < 4; ++nt) {
        const int p = nt * 16 + lm, y = p >> 3, x = p & 7;
        const int pix = (y + 1) * 10 + (x + 1);
        #pragma unroll
        for (int r = 0; r < 4; ++r) {
            const int oc = 16 * w + lq * 4 + r;
            float v = c1[nt][r];
            v = (v >= 0.f) ? v : SLOPE * v;
            H1T[pix * 72 + oc] = (short)f2bf(v);
        }
    }

    // prefetch conv2 A-operand (global, independent of H1T) before barrier
    s8v wa0, wa1;
    const short* wrow = w2b + (size_t)((w & 1) * 16 + lm) * 576 + lq * 8;
    if (w < 2) {
        wa0 = *(const s8v*)(wrow);
        wa1 = *(const s8v*)(wrow + 32);
    }
    __syncthreads();

    // ---- phase 5: conv2 MFMA, full K=576 on waves 0,1; B read from H1T
    // directly: B[p2][k2=tap*64+c] = H1T[pix(tap,p2)*72 + c]
    if (w < 2) {
        f4v c2 = (f4v){0.f, 0.f, 0.f, 0.f};
        const short* hbase = H1T + (20 * (lm >> 2) + 2 * (lm & 3)) * 72 + lq * 8;
        #pragma unroll
        for (int ks = 0; ks < 18; ++ks) {
            const int tap = ks >> 1;
            const int ky = tap / 3, kx = tap - 3 * ky;       // compile-time
            s8v a = (ks == 0) ? wa0 : (ks == 1) ? wa1
                  : *(const s8v*)(wrow + ks * 32);
            s8v bb = *(const s8v*)(hbase + (ky * 10 + kx) * 72 + (ks & 1) * 32);
            c2 = MFMA(a, bb, c2);
        }
        #pragma unroll
        for (int r = 0; r < 4; ++r) {
            const int oc = w * 16 + lq * 4 + r;
            float v = c2[r];
            h2pre[(size_t)b * 512 + oc * 16 + lm] = v;
            float s1 = v, s2 = v * v;
            #pragma unroll
            for (int m = 1; m < 16; m <<= 1) {
                s1 += __shfl_xor(s1, m, 16);
                s2 += __shfl_xor(s2, m, 16);
            }
            if (lm == 0) { CS[oc] = s1; CS2[oc] = s2; }
        }
    }
    __syncthreads();
    if (t < 64) {                         // replicated: 32 RMWs/address
        const float v = (t < 32) ? CS[t] : CS2[t - 32];
        atomicAdd(&bn2r[(b & 63) * 64 + t], v);
    }
}

// ---------------------------------------------------------------------------
// stage2: 4 b per block. reduce bn2 replicas, BN2+lrelu, conv3, BN3 partial
// -> replicated bn3r[blockIdx&31][32]
// ---------------------------------------------------------------------------
__global__ __launch_bounds__(256) void stage2(
    const float* __restrict__ h2pre,
    const float* __restrict__ gamma2, const float* __restrict__ beta2,
    const float* __restrict__ w3,
    const float* __restrict__ bn2r,
    float* __restrict__ h3pre,
    float* __restrict__ bn3r, int B)
{
    const int b0 = blockIdx.x * 4, t = threadIdx.x;
    __shared__ float s_sums[64];
    __shared__ float s_scale[32], s_shift[32];
    __shared__ float s_pad[4 * 32 * 36];
    __shared__ float s_c3[16], s_c32[16];

    if (t < 64) {                          // reduce 64 replicas
        float s = 0.f;
        #pragma unroll
        for (int r = 0; r < 64; ++r) s += bn2r[r * 64 + t];
        s_sums[t] = s;
    }
    if (t < 16) { s_c3[t] = 0.f; s_c32[t] = 0.f; }
    for (int i = t; i < 4 * 32 * 36; i += 256) s_pad[i] = 0.f;
    __syncthreads();

    if (t < 32) {
        const float n = (float)B * 16.f;
        const float mean = s_sums[t] / n;
        const float var  = s_sums[32 + t] / n - mean * mean;
        const float sc   = gamma2[t] * rsqrtf(var + BN_EPS);
        s_scale[t] = sc;
        s_shift[t] = beta2[t] - mean * sc;
    }
    __syncthreads();

    for (int i = t; i < 2048; i += 256) {
        const int lb = i >> 9, r = i & 511;
        const int c = r >> 4, p = r & 15, y = p >> 2, x = p & 3;
        const float v = h2pre[(size_t)b0 * 512 + i] * s_scale[c] + s_shift[c];
        const float a = (v >= 0.f) ? v : SLOPE * v;
        s_pad[lb * 1152 + c * 36 + (y + 1) * 6 + (x + 1)] = a;
    }
    __syncthreads();

    {
        const int lb = t >> 6, r = t & 63;
        const int oc = r >> 2, p = r & 3, y = p >> 1, x = p & 1;
        float acc = 0.f;
        const float* wp = w3 + oc * 288;
        const float* hp = &s_pad[lb * 1152];
        for (int c = 0; c < 32; ++c) {
            const float* hc = hp + c * 36;
            #pragma unroll
            for (int ky = 0; ky < 3; ++ky)
                #pragma unroll
                for (int kx = 0; kx < 3; ++kx)
                    acc += wp[c * 9 + ky * 3 + kx] * hc[(2 * y + ky) * 6 + (2 * x + kx)];
        }
        h3pre[(size_t)b0 * 64 + t] = acc;
        atomicAdd(&s_c3[oc],  acc);
        atomicAdd(&s_c32[oc], acc * acc);
    }
    __syncthreads();
    if (t < 32) {                          // replicated: 16 RMWs/address
        const float v = (t < 16) ? s_c3[t] : s_c32[t - 16];
        atomicAdd(&bn3r[(blockIdx.x & 31) * 32 + t], v);
    }
}

// ---------------------------------------------------------------------------
// stage3: reduce bn3 replicas, BN3 + lrelu -> out
// ---------------------------------------------------------------------------
__global__ __launch_bounds__(256) void stage3(
    const float* __restrict__ h3pre,
    const float* __restrict__ gamma3, const float* __restrict__ beta3,
    const float* __restrict__ bn3r,
    float* __restrict__ out, int total, int B)
{
    __shared__ float s_tmp[32];
    __shared__ float s_scale[16], s_shift[16];
    if (threadIdx.x < 32) {                // reduce 32 replicas
        float s = 0.f;
        #pragma unroll
        for (int r = 0; r < 32; ++r) s += bn3r[r * 32 + threadIdx.x];
        s_tmp[threadIdx.x] = s;
    }
    __syncthreads();
    if (threadIdx.x < 16) {
        const int c = threadIdx.x;
        const float n = (float)B * 4.f;
        const float mean = s_tmp[c] / n;
        const float var  = s_tmp[16 + c] / n - mean * mean;
        const float sc   = gamma3[c] * rsqrtf(var + BN_EPS);
        s_scale[c] = sc;
        s_shift[c] = beta3[c] - mean * sc;
    }
    __syncthreads();
    const int idx = blockIdx.x * 256 + threadIdx.x;
    if (idx < total) {
        const int c = (idx & 63) >> 2;
        const float v = h3pre[idx] * s_scale[c] + s_shift[c];
        out[idx] = (v >= 0.f) ? v : SLOPE * v;
    }
}

extern "C" void kernel_launch(void* const* d_in, const int* in_sizes, int n_in,
                              void* d_out, int out_size, void* d_ws, size_t ws_size,
                              hipStream_t stream)
{
    const float* labels = (const float*)d_in[0];
    const float* theta  = (const float*)d_in[1];
    const float* w1     = (const float*)d_in[2];
    const float* w2     = (const float*)d_in[3];
    const float* gamma2 = (const float*)d_in[4];
    const float* beta2  = (const float*)d_in[5];
    const float* w3     = (const float*)d_in[6];
    const float* gamma3 = (const float*)d_in[7];
    const float* beta3  = (const float*)d_in[8];
    const int*   maxobj = (const int*)d_in[9];

    const int B = in_sizes[0] / (O_MAX * C_DIM);   // 2048

    unsigned char* ws = (unsigned char*)d_ws;
    float* h2pre = (float*)ws;                                  // B*512 f32
    float* h3pre = h2pre + (size_t)B * 512;                     // B*64
    float* sums  = h3pre + (size_t)B * 64;                      // 5120
    short* w1n   = (short*)(sums + N_SUMS);                     // 73728 sh
    short* w2b   = w1n + N_W1N;                                 // 18432 sh
    float* bn2r  = sums;                                        // [64][64]
    float* bn3r  = sums + 4096;                                 // [32][32]

    const int prep_total = N_W1N + N_W2B + N_SUMS;
    prep<<<(prep_total + 255) / 256, 256, 0, stream>>>(w1, w2, w1n, w2b, sums);
    stage1<<<B, 256, 0, stream>>>(labels, theta, w1n, w2b, maxobj,
                                  h2pre, bn2r);
    stage2<<<B / 4, 256, 0, stream>>>(h2pre, gamma2, beta2, w3, bn2r,
                                      h3pre, bn3r, B);
    const int total = B * 64;
    stage3<<<(total + 255) / 256, 256, 0, stream>>>(h3pre, gamma3, beta3,
                                                    bn3r, (float*)d_out,
                                                    total, B);
}